// Round 5
// baseline (64.214 us; speedup 1.0000x reference)
//
#include <hip/hip_runtime.h>

#define D 256
#define WAVES_PER_BLOCK 4

// Wave-local LDS fence: tree buffer is wave-private (guide rule #18).
__device__ __forceinline__ void lds_fence() {
    asm volatile("s_waitcnt lgkmcnt(0)" ::: "memory");
    __builtin_amdgcn_sched_barrier(0);
}

template<int CTRL>
__device__ __forceinline__ float dpp0(float v) {
    return __int_as_float(__builtin_amdgcn_update_dpp(
        0, __float_as_int(v), CTRL, 0xF, 0xF, true));
}

// Full wave64 sum via DPP (VALU pipe, no DS ops).
__device__ __forceinline__ float wave_sum_dpp(float v) {
    v += dpp0<0x111>(v);
    v += dpp0<0x112>(v);
    v += dpp0<0x114>(v);
    v += dpp0<0x118>(v);
    v += dpp0<0x142>(v);
    v += dpp0<0x143>(v);
    return __int_as_float(__builtin_amdgcn_readlane(__float_as_int(v), 63));
}

// ROUND-5 ABLATION BUILD: identical algorithm to round 4, plus 6 DUMMY row
// gathers per pair (3x extra memory traffic, 105 -> 419 MB). Dummy data is
// folded into a register and kept live via asm volatile (rule #17) but never
// touches the output. Purpose: quantify the marginal cost of the random row
// gather, g = (dur - 22.7us) / 3, to decide memory-side vs compute-side next.
__global__ __launch_bounds__(256) void poincare_tree_l1_kernel(
    const float* __restrict__ weight,
    const int*   __restrict__ xi,
    const int*   __restrict__ yi,
    float*       __restrict__ out,
    int npairs,
    int nrows)
{
    __shared__ __align__(16) float sbuf[WAVES_PER_BLOCK][D];

    const int wave = threadIdx.x >> 6;
    const int lane = threadIdx.x & 63;
    const int pair = blockIdx.x * WAVES_PER_BLOCK + wave;
    const int p = pair < npairs ? pair : npairs - 1;

    const int ix = xi[p];
    const int iy = yi[p];

    // Dummy gather indices: pseudo-random, distinct from ix/iy, in-range.
    int j1 = ix + 33331; if (j1 >= nrows) j1 -= nrows;
    int j2 = iy + 33331; if (j2 >= nrows) j2 -= nrows;
    int j3 = ix + 66661; if (j3 >= nrows) j3 -= nrows;
    int j4 = iy + 66661; if (j4 >= nrows) j4 -= nrows;
    int j5 = ix + 12347; if (j5 >= nrows) j5 -= nrows;
    int j6 = iy + 12347; if (j6 >= nrows) j6 -= nrows;

    const float4 ax = ((const float4*)(weight + (size_t)ix * D))[lane];
    const float4 ay = ((const float4*)(weight + (size_t)iy * D))[lane];
    const float4 b1 = ((const float4*)(weight + (size_t)j1 * D))[lane];
    const float4 b2 = ((const float4*)(weight + (size_t)j2 * D))[lane];
    const float4 b3 = ((const float4*)(weight + (size_t)j3 * D))[lane];
    const float4 b4 = ((const float4*)(weight + (size_t)j4 * D))[lane];
    const float4 b5 = ((const float4*)(weight + (size_t)j5 * D))[lane];
    const float4 b6 = ((const float4*)(weight + (size_t)j6 * D))[lane];

    // Sink the dummy data (kept live, zero output effect).
    float dacc = (b1.x + b1.y + b1.z + b1.w) + (b2.x + b2.y + b2.z + b2.w)
               + (b3.x + b3.y + b3.z + b3.w) + (b4.x + b4.y + b4.z + b4.w)
               + (b5.x + b5.y + b5.z + b5.w) + (b6.x + b6.y + b6.z + b6.w);
    asm volatile("" :: "v"(dacc));

    const float ex0 = __expf(ax.x), ex1 = __expf(ax.y);
    const float ex2 = __expf(ax.z), ex3 = __expf(ax.w);
    const float ey0 = __expf(ay.x), ey1 = __expf(ay.y);
    const float ey2 = __expf(ay.z), ey3 = __expf(ay.w);

    const float invx = 1.0f / wave_sum_dpp((ex0 + ex1) + (ex2 + ex3));
    const float invy = 1.0f / wave_sum_dpp((ey0 + ey1) + (ey2 + ey3));

    const float d0 = ex0 * invx - ey0 * invy;
    const float d1 = ex1 * invx - ey1 * invy;
    const float d2 = ex2 * invx - ey2 * invy;
    const float d3 = ex3 * invx - ey3 * invy;

    // Leaf terms (nodes 85..255) straight from registers.
    float acc = 0.0f;
    if (lane >= 22) acc  = fabsf(d0);
    if (lane >= 21) acc += fabsf(d1) + fabsf(d2) + fabsf(d3);

    float* s = sbuf[wave];
    ((float4*)s)[lane] = make_float4(d0, d1, d2, d3);
    lds_fence();

    // Bottom-up subtree accumulation, internal nodes [0,84] by level.
    if (lane < 45) {
        const int j = 40 + lane;
        const float v = s[j] + s[3*j+1] + s[3*j+2] + s[3*j+3];
        s[j] = v; acc += fabsf(v);
    }
    lds_fence();
    if (lane < 27) {
        const int j = 13 + lane;
        const float v = s[j] + s[3*j+1] + s[3*j+2] + s[3*j+3];
        s[j] = v; acc += fabsf(v);
    }
    lds_fence();
    if (lane < 9) {
        const int j = 4 + lane;
        const float v = s[j] + s[3*j+1] + s[3*j+2] + s[3*j+3];
        s[j] = v; acc += fabsf(v);
    }
    lds_fence();
    if (lane < 3) {
        const int j = 1 + lane;
        const float v = s[j] + s[3*j+1] + s[3*j+2] + s[3*j+3];
        s[j] = v; acc += fabsf(v);
    }
    lds_fence();
    if (lane == 0) {
        const float v = s[0] + s[1] + s[2] + s[3];
        acc += fabsf(v);
    }

    const float total = wave_sum_dpp(acc);

    if (lane == 0 && pair < npairs) out[pair] = total;
}

extern "C" void kernel_launch(void* const* d_in, const int* in_sizes, int n_in,
                              void* d_out, int out_size, void* d_ws, size_t ws_size,
                              hipStream_t stream) {
    const float* weight = (const float*)d_in[0];
    const int*   xi     = (const int*)d_in[1];
    const int*   yi     = (const int*)d_in[2];
    float*       out    = (float*)d_out;

    const int npairs = out_size;           // 1024*50 = 51200 pairs
    const int nrows  = in_sizes[0] / D;    // 100000 embedding rows
    const int blocks = (npairs + WAVES_PER_BLOCK - 1) / WAVES_PER_BLOCK;

    poincare_tree_l1_kernel<<<blocks, 256, 0, stream>>>(weight, xi, yi, out,
                                                        npairs, nrows);
}

// Round 6
// 22.724 us; speedup vs baseline: 2.8258x; 2.8258x over previous
//
#include <hip/hip_runtime.h>

#define D 256
#define WAVES_PER_BLOCK 4
#define LDS_STRIDE 260   // 257 P-values padded to a 16B multiple

// Wave-local LDS fence: P buffer is wave-private (guide rule #18).
__device__ __forceinline__ void lds_fence() {
    asm volatile("s_waitcnt lgkmcnt(0)" ::: "memory");
    __builtin_amdgcn_sched_barrier(0);
}

// DPP source term: shifted/broadcast value, 0 for masked-off rows / OOB lanes
// (old=0, bound_ctrl=1). Adding it leaves masked-off lanes unchanged.
template<int CTRL, int RM>
__device__ __forceinline__ float dpp_term(float v) {
    return __int_as_float(__builtin_amdgcn_update_dpp(
        0, __float_as_int(v), CTRL, RM, 0xF, true));
}

// Canonical GCN wave64 inclusive scan (VALU pipe, no DS ops):
// row_shr 1/2/4/8 scan within 16-lane rows, row_bcast15 (rows 1,3),
// row_bcast31 (rows 2,3) stitch rows together.
__device__ __forceinline__ float wave_scan_incl(float v) {
    v += dpp_term<0x111, 0xF>(v);
    v += dpp_term<0x112, 0xF>(v);
    v += dpp_term<0x114, 0xF>(v);
    v += dpp_term<0x118, 0xF>(v);
    v += dpp_term<0x142, 0xa>(v);  // row1 += lane15, row3 += lane47
    v += dpp_term<0x143, 0xc>(v);  // rows 2,3 += lane31
    return v;
}

__device__ __forceinline__ float wave_sum_dpp(float v) {
    return __int_as_float(__builtin_amdgcn_readlane(
        __float_as_int(wave_scan_incl(v)), 63));
}

// One wave per (b,s) pair; lane l owns elements [4l,4l+3] (one float4/row).
//
// Subtree-sum via PREFIX SUMS: in heap indexing the subtree of node j is a
// union of contiguous ranges ([j], [3j+1,3j+3], [9j+4,9j+12], [27j+13,27j+39],
// [81j+40,81j+120], clamped to 255), so S[j] = sum of P-differences where
// P = exclusive prefix sum of d = px - py. P is built with a DPP wave scan
// and written to LDS ONCE; all internal-node sums are then independent
// gathers -> 2 LDS fences total and no level-by-level serial chain.
// S[0] = sum(d) = 1 - 1 = 0 exactly -> skipped.
// Leaves (nodes 85..255) contribute |d[e]| straight from registers.
__global__ __launch_bounds__(256) void poincare_tree_l1_kernel(
    const float* __restrict__ weight,
    const int*   __restrict__ xi,
    const int*   __restrict__ yi,
    float*       __restrict__ out,
    int npairs)
{
    __shared__ __align__(16) float sbuf[WAVES_PER_BLOCK][LDS_STRIDE];

    const int wave = threadIdx.x >> 6;
    const int lane = threadIdx.x & 63;
    const int pair = blockIdx.x * WAVES_PER_BLOCK + wave;
    const int p = pair < npairs ? pair : npairs - 1;  // grid divides exactly

    const int ix = xi[p];
    const int iy = yi[p];

    const float4 ax = ((const float4*)(weight + (size_t)ix * D))[lane];
    const float4 ay = ((const float4*)(weight + (size_t)iy * D))[lane];

    // exp (weights ~ N(0,1): softmax without max-subtraction is exact-safe)
    const float ex0 = __expf(ax.x), ex1 = __expf(ax.y);
    const float ex2 = __expf(ax.z), ex3 = __expf(ax.w);
    const float ey0 = __expf(ay.x), ey1 = __expf(ay.y);
    const float ey2 = __expf(ay.z), ey3 = __expf(ay.w);

    const float invx = 1.0f / wave_sum_dpp((ex0 + ex1) + (ex2 + ex3));
    const float invy = 1.0f / wave_sum_dpp((ey0 + ey1) + (ey2 + ey3));

    const float d0 = ex0 * invx - ey0 * invy;
    const float d1 = ex1 * invx - ey1 * invy;
    const float d2 = ex2 * invx - ey2 * invy;
    const float d3 = ex3 * invx - ey3 * invy;

    // Leaf terms: element e = 4*lane+k is a leaf iff e >= 85.
    float acc = 0.0f;
    if (lane >= 22) acc  = fabsf(d0);
    if (lane >= 21) acc += fabsf(d1) + fabsf(d2) + fabsf(d3);

    // Exclusive prefix sum P of d: in-register DPP scan of per-lane sums.
    const float local = (d0 + d1) + (d2 + d3);
    const float incl  = wave_scan_incl(local);
    const float base  = incl - local;          // P[4*lane]
    const float p1 = base + d0;
    const float p2 = p1 + d1;
    const float p3 = p2 + d2;

    float* s = sbuf[wave];
    ((float4*)s)[lane] = make_float4(base, p1, p2, p3);  // P[4l..4l+3]
    if (lane == 63) s[D] = incl;                         // P[256] = total
    lds_fence();

    // Pass A: node j = 21 + lane  (j in [21,84] -- all of L4-internal + upper L3).
    {
        const int j = 21 + lane;
        float sA = (s[j + 1] - s[j]) + (s[3 * j + 4] - s[3 * j + 1]);
        if (j <= 27) sA += s[9 * j + 13] - s[9 * j + 4];   // j in [21,27] has L+2 range
        acc += fabsf(sA);
    }
    // Pass B: node j = lane for j in [1,20] (L1, L2, lower L3).
    if (lane >= 1 && lane <= 20) {
        const int j = lane;
        float sB = (s[j + 1] - s[j]) + (s[3 * j + 4] - s[3 * j + 1])
                 + (s[9 * j + 13] - s[9 * j + 4]);
        if (j <= 8) sB += s[27 * j + 40] - s[27 * j + 13];
        if (j <= 3) {
            int a = 81 * j + 40;  if (a > 256) a = 256;    // clamp partial last level
            int b = 81 * j + 121; if (b > 256) b = 256;
            sB += s[b] - s[a];
        }
        acc += fabsf(sB);
    }

    const float total = wave_sum_dpp(acc);
    if (lane == 0 && pair < npairs) out[pair] = total;
}

extern "C" void kernel_launch(void* const* d_in, const int* in_sizes, int n_in,
                              void* d_out, int out_size, void* d_ws, size_t ws_size,
                              hipStream_t stream) {
    const float* weight = (const float*)d_in[0];
    const int*   xi     = (const int*)d_in[1];
    const int*   yi     = (const int*)d_in[2];
    float*       out    = (float*)d_out;

    const int npairs = out_size;  // 1024*50 = 51200 (b,s) pairs
    const int blocks = (npairs + WAVES_PER_BLOCK - 1) / WAVES_PER_BLOCK;

    poincare_tree_l1_kernel<<<blocks, 256, 0, stream>>>(weight, xi, yi, out, npairs);
}

// Round 7
// 22.194 us; speedup vs baseline: 2.8933x; 1.0239x over previous
//
#include <hip/hip_runtime.h>

#define D 256
#define WAVES_PER_BLOCK 4
#define LDS_STRIDE 260   // 257 P-values padded to a 16B multiple

// Wave-local LDS fence: P buffers are wave-private (guide rule #18).
__device__ __forceinline__ void lds_fence() {
    asm volatile("s_waitcnt lgkmcnt(0)" ::: "memory");
    __builtin_amdgcn_sched_barrier(0);
}

// DPP source term: shifted/broadcast value, 0 for masked-off rows / OOB lanes
// (old=0, bound_ctrl=1). Adding it leaves masked-off lanes unchanged.
template<int CTRL, int RM>
__device__ __forceinline__ float dpp_term(float v) {
    return __int_as_float(__builtin_amdgcn_update_dpp(
        0, __float_as_int(v), CTRL, RM, 0xF, true));
}

// Canonical GCN wave64 inclusive scan (VALU pipe, no DS ops).
__device__ __forceinline__ float wave_scan_incl(float v) {
    v += dpp_term<0x111, 0xF>(v);
    v += dpp_term<0x112, 0xF>(v);
    v += dpp_term<0x114, 0xF>(v);
    v += dpp_term<0x118, 0xF>(v);
    v += dpp_term<0x142, 0xa>(v);  // row1 += lane15, row3 += lane47
    v += dpp_term<0x143, 0xc>(v);  // rows 2,3 += lane31
    return v;
}

__device__ __forceinline__ float wave_sum_bcast(float v) {
    return __int_as_float(__builtin_amdgcn_readlane(
        __float_as_int(wave_scan_incl(v)), 63));
}

// Phase 1 (register-only until the single LDS write): softmax difference
// d = px - py, leaf |d| terms (nodes 85..255), exclusive prefix sums of d
// written to this pair's wave-private LDS buffer. Returns leaf acc.
// Weights ~ N(0,1): softmax without max-subtraction is safe in fp32.
__device__ __forceinline__ float phase1(const float4 ax, const float4 ay,
                                        const int lane, float* __restrict__ s)
{
    const float ex0 = __expf(ax.x), ex1 = __expf(ax.y);
    const float ex2 = __expf(ax.z), ex3 = __expf(ax.w);
    const float ey0 = __expf(ay.x), ey1 = __expf(ay.y);
    const float ey2 = __expf(ay.z), ey3 = __expf(ay.w);

    const float invx = 1.0f / wave_sum_bcast((ex0 + ex1) + (ex2 + ex3));
    const float invy = 1.0f / wave_sum_bcast((ey0 + ey1) + (ey2 + ey3));

    const float d0 = ex0 * invx - ey0 * invy;
    const float d1 = ex1 * invx - ey1 * invy;
    const float d2 = ex2 * invx - ey2 * invy;
    const float d3 = ex3 * invx - ey3 * invy;

    // element e = 4*lane+k is a leaf iff e >= 85
    float acc = 0.0f;
    if (lane >= 22) acc  = fabsf(d0);
    if (lane >= 21) acc += fabsf(d1) + fabsf(d2) + fabsf(d3);

    const float local = (d0 + d1) + (d2 + d3);
    const float incl  = wave_scan_incl(local);
    const float base  = incl - local;          // P[4*lane]
    ((float4*)s)[lane] = make_float4(base, base + d0, base + d0 + d1,
                                     base + d0 + d1 + d2);
    if (lane == 63) s[D] = incl;               // P[256] = total
    return acc;
}

// Phase 2: internal-node subtree sums (nodes 1..84; node 0 sums to 0 exactly)
// as telescoping differences of the prefix array. Independent gathers, no
// level-by-level chain.
__device__ __forceinline__ float phase2(const float* __restrict__ s, const int lane)
{
    float acc;
    {   // nodes j in [21,84]
        const int j = 21 + lane;
        float sA = (s[j + 1] - s[j]) + (s[3 * j + 4] - s[3 * j + 1]);
        if (j <= 27) sA += s[9 * j + 13] - s[9 * j + 4];
        acc = fabsf(sA);
    }
    if (lane >= 1 && lane <= 20) {  // nodes j in [1,20]
        const int j = lane;
        float sB = (s[j + 1] - s[j]) + (s[3 * j + 4] - s[3 * j + 1])
                 + (s[9 * j + 13] - s[9 * j + 4]);
        if (j <= 8) sB += s[27 * j + 40] - s[27 * j + 13];
        if (j <= 3) {
            int a = 81 * j + 40;  if (a > 256) a = 256;   // clamp partial level
            int b = 81 * j + 121; if (b > 256) b = 256;
            sB += s[b] - s[a];
        }
        acc += fabsf(sB);
    }
    return acc;
}

// TWO (b,s) pairs per wave: all four 1 KB row gathers are issued back-to-back
// before any dependent use, doubling in-flight bytes per wave (MLP). Round-5
// ablation showed per-CU gather throughput rises with outstanding loads
// (7.5 -> 10.6 B/cy/CU going 2 -> 8 loads/wave); compute is fully hidden
// (rounds 4 and 6: two different compute structures, identical 22.7 us).
__global__ __launch_bounds__(256) void poincare_tree_l1_kernel(
    const float* __restrict__ weight,
    const int*   __restrict__ xi,
    const int*   __restrict__ yi,
    float*       __restrict__ out,
    int npairs)
{
    __shared__ __align__(16) float sbuf[WAVES_PER_BLOCK][2][LDS_STRIDE];

    const int wave = threadIdx.x >> 6;
    const int lane = threadIdx.x & 63;
    const int gw   = blockIdx.x * WAVES_PER_BLOCK + wave;
    const int p0   = 2 * gw;
    const int p1   = p0 + 1;
    const int q0   = p0 < npairs ? p0 : npairs - 1;   // clamps (npairs even)
    const int q1   = p1 < npairs ? p1 : npairs - 1;

    const int ix0 = xi[q0], iy0 = yi[q0];
    const int ix1 = xi[q1], iy1 = yi[q1];

    const float4 ax0 = ((const float4*)(weight + (size_t)ix0 * D))[lane];
    const float4 ay0 = ((const float4*)(weight + (size_t)iy0 * D))[lane];
    const float4 ax1 = ((const float4*)(weight + (size_t)ix1 * D))[lane];
    const float4 ay1 = ((const float4*)(weight + (size_t)iy1 * D))[lane];

    float* sA = sbuf[wave][0];
    float* sB = sbuf[wave][1];

    // Two independent instruction streams; compiler interleaves their
    // reduction chains (2x ILP on the DPP/VALU critical path).
    float acc0 = phase1(ax0, ay0, lane, sA);
    float acc1 = phase1(ax1, ay1, lane, sB);
    lds_fence();
    acc0 += phase2(sA, lane);
    acc1 += phase2(sB, lane);

    const float t0 = wave_scan_incl(acc0);   // totals land in lane 63
    const float t1 = wave_scan_incl(acc1);

    if (lane == 63) {
        if (p1 < npairs) {
            ((float2*)(out + p0))[0] = make_float2(t0, t1);  // adjacent pairs
        } else if (p0 < npairs) {
            out[p0] = t0;
        }
    }
}

extern "C" void kernel_launch(void* const* d_in, const int* in_sizes, int n_in,
                              void* d_out, int out_size, void* d_ws, size_t ws_size,
                              hipStream_t stream) {
    const float* weight = (const float*)d_in[0];
    const int*   xi     = (const int*)d_in[1];
    const int*   yi     = (const int*)d_in[2];
    float*       out    = (float*)d_out;

    const int npairs = out_size;  // 1024*50 = 51200 (b,s) pairs
    const int nwaves = (npairs + 1) / 2;
    const int blocks = (nwaves + WAVES_PER_BLOCK - 1) / WAVES_PER_BLOCK;

    poincare_tree_l1_kernel<<<blocks, 256, 0, stream>>>(weight, xi, yi, out, npairs);
}